// Round 8
// baseline (387.817 us; speedup 1.0000x reference)
//
#include <hip/hip_runtime.h>
#include <math.h>

// SSM_18597208391915: HiPPO-LegT recurrence, O(N) semiseparable solve.
// Ad = (I-cA)^{-1}(I+cA) = 2M - I  =>  h' = tanh(2*M(h + c*u*P) - h).
// R8: CHUNKED SKEWED 2-WAVE PIPELINE. R7 showed the single wave is ~85%
// issue-saturated on its SIMD (VALUBusy 42% CU-avg = 2 of 4 SIMDs busy).
// Split hidden dim over NW=2 waves (1024 waves = 1/SIMD, all SIMDs busy),
// halving per-wave issue. Inter-wave dep = ONE scalar/step (wave0's
// inclusive affine-B), one-directional (A lower-triangular). Chunked skew:
// wave0 runs 16-step chunks publishing B-totals to LDS, ONE barrier per
// chunk (R6's per-step barrier cost ~1067 cyc/tick killed it; here it's
// amortized 16x). Wave1 lags one chunk; tot_s[s] always crosses >=1
// barrier (race-free). State kept as r = 1/(1+e^{2g}) (h = 1-2r): negh/au
// precompute issues in the scan-phase latency bubble, post-rcp chain = 2.

#define SEQ     784
#define OUT_DIM 10
#define NW      2
#define CH      16            // steps per chunk
#define NCH     (SEQ/CH)      // 49
#define EPL     8             // elems/lane: NW*64*EPL = 1024 = HIDDEN
#define NG      (EPL/2)

typedef float v2f __attribute__((ext_vector_type(2)));

#if __has_builtin(__builtin_elementwise_fma)
__device__ __forceinline__ v2f fma2(v2f a, v2f b, v2f c) {
    return __builtin_elementwise_fma(a, b, c);
}
#else
__device__ __forceinline__ v2f fma2(v2f a, v2f b, v2f c) {
    v2f r; r.x = fmaf(a.x, b.x, c.x); r.y = fmaf(a.y, b.y, c.y); return r;
}
#endif

#if __has_builtin(__builtin_amdgcn_exp2f)
#define EXP2F(x) __builtin_amdgcn_exp2f(x)
#else
#define EXP2F(x) __expf(0.69314718055994531f * (x))
#endif

// DPP move: result = src shuffled per CTRL; invalid/masked lanes get `old`.
template<int CTRL, int ROW_MASK>
__device__ __forceinline__ float dpp_mov(float src, float old) {
    return __int_as_float(__builtin_amdgcn_update_dpp(
        __float_as_int(old), __float_as_int(src), CTRL, ROW_MASK, 0xf, false));
}
// DPP ctrls: row_shr:N = 0x110|N, row_bcast15 = 0x142, row_bcast31 = 0x143,
//            wave_shr:1 = 0x138 (whole-wave shift down one lane)

__global__ __launch_bounds__(128, 1)
void ssm_hippo_scan(const float* __restrict__ x,     // (512, 784)
                    const float* __restrict__ C,     // (1024)
                    const float* __restrict__ W,     // (10)
                    const float* __restrict__ bvec,  // (10)
                    float* __restrict__ out)         // (512, 10)
{
    const int b    = blockIdx.x;
    const int tid  = threadIdx.x;
    const int wv   = tid >> 6;       // 0: elems 0..511, 1: elems 512..1023
    const int lane = tid & 63;

    __shared__ float  u_s[SEQ + 1];
    __shared__ float  tot_s[SEQ];    // wave0's inclusive affine-B per step
    __shared__ double part_s[NW];

    for (int t = tid; t < SEQ; t += 128) u_s[t] = x[b * SEQ + t];
    if (tid == 0) u_s[SEQ] = 0.0f;

    const double hdt  = 0.5 / (double)SEQ;            // c = dt/2
    const double L2E2 = 2.0 * 1.4426950408889634;     // 2*log2(e)

    // ---- per-element constants (n = wv*512 + lane*EPL + i), fp64-derived
    v2f upc2[NG], nhdtP2[NG], pdin2[NG], invd2v[NG], aprod2[NG], aprel2[2];
    float alphas[EPL], apH;
    float Alev0, Alev1, Alev2, Alev3, Alev4, Alev5, Aexcl;
    {
        double apd = 1.0, ap4 = 1.0;
        double aprd[EPL];
#pragma unroll
        for (int i = 0; i < EPL; ++i) {
            const int    n = wv * 512 + lane * EPL + i;
            const double p = sqrt(1.0 + 2.0 * (double)n);
            const double d = 1.0 + hdt * (double)(n + 1);
            const double a = 1.0 - hdt * p * p / d;
            upc2[i>>1][i&1]   = (float)(L2E2 * hdt * p);
            nhdtP2[i>>1][i&1] = (float)(-hdt * p);
            pdin2[i>>1][i&1]  = (float)(p / d);
            invd2v[i>>1][i&1] = (float)(2.0 / d);
            alphas[i]         = (float)a;
            aprd[i] = apd;
            aprod2[i>>1][i&1] = (float)apd;
            apd *= a;
            if (i == 4) ap4 = aprd[4];
        }
        apH = (float)(apd / ap4);
#pragma unroll
        for (int i = 4; i < EPL; ++i)
            aprel2[(i-4)>>1][i&1] = (float)(aprd[i] / ap4);
        float A = (float)apd;
        Alev0 = A; A *= dpp_mov<0x111, 0xf>(A, 1.0f);
        Alev1 = A; A *= dpp_mov<0x112, 0xf>(A, 1.0f);
        Alev2 = A; A *= dpp_mov<0x114, 0xf>(A, 1.0f);
        Alev3 = A; A *= dpp_mov<0x118, 0xf>(A, 1.0f);
        Alev4 = A; A *= dpp_mov<0x142, 0xa>(A, 1.0f);
        Alev5 = A; A *= dpp_mov<0x143, 0xc>(A, 1.0f);
        Aexcl = dpp_mov<0x138, 0xf>(A, 1.0f);   // lane0 -> 1 (excl alpha prod)
    }

    const float c2  = (float)L2E2;           //  2*log2e
    const float nc4 = (float)(-2.0 * L2E2);  // -4*log2e  (Hs = nc4*r + c2)
    const float p4  = (float)(2.0 * L2E2);   //  (-Hs = p4*r - c2)
    const v2f  c2v  = (v2f){c2, c2},  nc2v = (v2f){-c2, -c2};
    const v2f  nc4v = (v2f){nc4, nc4}, p4v = (v2f){p4, p4};

    __syncthreads();                         // u_s ready

    // ---- state: r (sigmoid form, h = 1-2r), current w & gamma
    v2f r2[NG], wv2[NG], gam2[NG];
    {
        const float u0 = u_s[0];
        const v2f  uu0 = (v2f){u0, u0};
#pragma unroll
        for (int j = 0; j < NG; ++j) {
            r2[j]   = (v2f){0.5f, 0.5f};                   // h = 0
            const v2f au = fma2(upc2[j], uu0, c2v);
            wv2[j]  = fma2(nc4v, r2[j], au);               // = upc*u0
            gam2[j] = pdin2[j] * wv2[j];
        }
    }

#pragma unroll 1
    for (int tick = 0; tick < NCH + NW - 1; ++tick) {
        const int ch = tick - wv;            // this wave's chunk index
        if (0 <= ch && ch < NCH) {
#pragma unroll 1
            for (int k = 0; k < CH; ++k) {
                const int s = ch * CH + k;
                // early long-latency LDS reads (consumed late in the step)
                const float u_nx = u_s[s + 1];
                float Tin = 0.0f;
                if (wv) Tin = tot_s[s];      // written >=1 barrier ago

                // scan-phase-shadow precompute (fills the latency bubble)
                v2f au_nx[NG], negh[NG];
                const v2f uu = (v2f){u_nx, u_nx};
#pragma unroll
                for (int j = 0; j < NG; ++j) {
                    au_nx[j] = fma2(upc2[j], uu, c2v);     // next step's u-part
                    negh[j]  = fma2(p4v, r2[j], nc2v);     // -Hs (this step)
                }

                // ---- local affine scan: two 4-deep chains + compose
                v2f Tb2[NG];
                float Tl0 = 0.0f, Tl1 = 0.0f;
#pragma unroll
                for (int i = 0; i < 4; ++i) {
                    Tb2[i>>1][i&1] = Tl0;
                    Tl0 = fmaf(alphas[i], Tl0, gam2[i>>1][i&1]);
                }
#pragma unroll
                for (int i = 4; i < EPL; ++i) {
                    Tb2[i>>1][i&1] = Tl1;
                    Tl1 = fmaf(alphas[i], Tl1, gam2[i>>1][i&1]);
                }
                const v2f T4 = (v2f){Tl0, Tl0};
                Tb2[2] = fma2(aprel2[0], T4, Tb2[2]);      // hi-half fixup
                Tb2[3] = fma2(aprel2[1], T4, Tb2[3]);
                float B = fmaf(apH, Tl0, Tl1);             // lane affine-B

                // ---- cross-lane affine scan (B chain, A's precomputed)
                float Bin;
                Bin = dpp_mov<0x111, 0xf>(B, 0.0f); B = fmaf(Alev0, Bin, B);
                Bin = dpp_mov<0x112, 0xf>(B, 0.0f); B = fmaf(Alev1, Bin, B);
                Bin = dpp_mov<0x114, 0xf>(B, 0.0f); B = fmaf(Alev2, Bin, B);
                Bin = dpp_mov<0x118, 0xf>(B, 0.0f); B = fmaf(Alev3, Bin, B);
                Bin = dpp_mov<0x142, 0xa>(B, 0.0f); B = fmaf(Alev4, Bin, B);
                Bin = dpp_mov<0x143, 0xc>(B, 0.0f); B = fmaf(Alev5, Bin, B);

                // wave0 publishes its full-wave inclusive B for step s
                if (wv == 0 && lane == 63) tot_s[s] = B;

                const float Tst  = dpp_mov<0x138, 0xf>(B, 0.0f); // excl shift
                const float Tent = fmaf(Aexcl, Tin, Tst);
                const v2f  Tev   = (v2f){Tent, Tent};

                // ---- elementwise tail, phase-separated
                v2f Tn[NG], tmp[NG], g2l[NG], e[NG];
#pragma unroll
                for (int j = 0; j < NG; ++j) Tn[j]  = fma2(aprod2[j], Tev, Tb2[j]);
#pragma unroll
                for (int j = 0; j < NG; ++j) tmp[j] = fma2(nhdtP2[j], Tn[j], wv2[j]);
#pragma unroll
                for (int j = 0; j < NG; ++j) g2l[j] = fma2(tmp[j], invd2v[j], negh[j]);
#pragma unroll
                for (int j = 0; j < NG; ++j) { e[j].x = EXP2F(g2l[j].x);
                                               e[j].y = EXP2F(g2l[j].y); }
#pragma unroll
                for (int j = 0; j < NG; ++j) e[j] = e[j] + (v2f){1.0f, 1.0f};
#pragma unroll
                for (int j = 0; j < NG; ++j) { r2[j].x = __builtin_amdgcn_rcpf(e[j].x);
                                               r2[j].y = __builtin_amdgcn_rcpf(e[j].y); }
#pragma unroll
                for (int j = 0; j < NG; ++j) {
                    wv2[j]  = fma2(nc4v, r2[j], au_nx[j]); // next step's w
                    gam2[j] = pdin2[j] * wv2[j];           // next step's gamma
                }
            }
        }
        __syncthreads();   // one barrier per CHUNK (16 steps)
    }

    // ---- epilogue: h = 1-2r; tot = dot(h, C) over this wave's 512 elems
    double acc = 0.0;
#pragma unroll
    for (int i = 0; i < EPL; ++i) {
        const float hi = fmaf(-2.0f, r2[i>>1][i&1], 1.0f);
        acc = fma((double)C[wv * 512 + lane * EPL + i], (double)hi, acc);
    }
#pragma unroll
    for (int off = 32; off > 0; off >>= 1)
        acc += __shfl_down(acc, off, 64);
    if (lane == 0) part_s[wv] = acc;
    __syncthreads();
    if (tid < OUT_DIM) {
        const double tot = part_s[0] + part_s[1];
        out[b * OUT_DIM + tid] =
            (float)fma(tot, (double)W[tid], (double)bvec[tid]);
    }
}

extern "C" void kernel_launch(void* const* d_in, const int* in_sizes, int n_in,
                              void* d_out, int out_size, void* d_ws, size_t ws_size,
                              hipStream_t stream) {
    const float* x  = (const float*)d_in[0];   // (512, 784, 1)
    const float* C  = (const float*)d_in[1];   // (1, 1024)
    const float* W  = (const float*)d_in[2];   // (1, 10)
    const float* bv = (const float*)d_in[3];   // (10,)
    float* out      = (float*)d_out;           // (512, 10)
    hipLaunchKernelGGL(ssm_hippo_scan, dim3(512), dim3(128), 0, stream,
                       x, C, W, bv, out);
}

// Round 9
// 351.778 us; speedup vs baseline: 1.1024x; 1.1024x over previous
//
#include <hip/hip_runtime.h>
#include <math.h>

// SSM_18597208391915: HiPPO-LegT recurrence, O(N) semiseparable solve.
// Ad = (I-cA)^{-1}(I+cA) = 2M - I  =>  h' = tanh(2*M(h + c*u*P) - h).
// R9: chunked skewed 2-wave pipeline (R8) with ZERO in-loop LDS.
// R8 post-mortem: per-wave VALU-busy correctly halved (786->440 cyc/step,
// ~65% of busy = 32 quarter-rate exp2/rcp at ~16cyc occupancy) but skew
// mechanics added ~500cyc/step stall: in-loop u_s/tot_s LDS reads + per-step
// predicated write + no co-wave to hide latency at 1 wave/SIMD. Fix: bulk
// register-buffer all chunk comms at tick boundaries (u: 4xfloat4; wave0's
// 16 B-totals: registers -> 4xfloat4 write once per chunk; wave1 reads them
// 4xfloat4 after the barrier). Fully-unrolled 16-step all-register inner
// loop; LDS latency amortized to ~15cyc/step at chunk edges.

#define SEQ     784
#define OUT_DIM 10
#define NW      2
#define CH      16            // steps per chunk
#define NCH     (SEQ/CH)      // 49
#define EPL     8             // elems/lane: NW*64*EPL = 1024 = HIDDEN
#define NG      (EPL/2)

typedef float v2f __attribute__((ext_vector_type(2)));

#if __has_builtin(__builtin_elementwise_fma)
__device__ __forceinline__ v2f fma2(v2f a, v2f b, v2f c) {
    return __builtin_elementwise_fma(a, b, c);
}
#else
__device__ __forceinline__ v2f fma2(v2f a, v2f b, v2f c) {
    v2f r; r.x = fmaf(a.x, b.x, c.x); r.y = fmaf(a.y, b.y, c.y); return r;
}
#endif

#if __has_builtin(__builtin_amdgcn_exp2f)
#define EXP2F(x) __builtin_amdgcn_exp2f(x)
#else
#define EXP2F(x) __expf(0.69314718055994531f * (x))
#endif

// DPP move: result = src shuffled per CTRL; invalid/masked lanes get `old`.
template<int CTRL, int ROW_MASK>
__device__ __forceinline__ float dpp_mov(float src, float old) {
    return __int_as_float(__builtin_amdgcn_update_dpp(
        __float_as_int(old), __float_as_int(src), CTRL, ROW_MASK, 0xf, false));
}
// DPP ctrls: row_shr:N = 0x110|N, row_bcast15 = 0x142, row_bcast31 = 0x143,
//            wave_shr:1 = 0x138 (whole-wave shift down one lane)

__global__ __launch_bounds__(128, 1)
void ssm_hippo_scan(const float* __restrict__ x,     // (512, 784)
                    const float* __restrict__ C,     // (1024)
                    const float* __restrict__ W,     // (10)
                    const float* __restrict__ bvec,  // (10)
                    float* __restrict__ out)         // (512, 10)
{
    const int b    = blockIdx.x;
    const int tid  = threadIdx.x;
    const int wv   = tid >> 6;       // 0: elems 0..511, 1: elems 512..1023
    const int lane = tid & 63;

    __shared__ __align__(16) float u_s[SEQ];
    __shared__ __align__(16) float totB_s[SEQ];  // wave0 inclusive-B per step
    __shared__ double part_s[NW];

    for (int t = tid; t < SEQ; t += 128) u_s[t] = x[b * SEQ + t];

    const double hdt  = 0.5 / (double)SEQ;            // c = dt/2
    const double L2E2 = 2.0 * 1.4426950408889634;     // 2*log2(e)

    // ---- per-element constants (n = wv*512 + lane*EPL + i), fp64-derived
    v2f upc2[NG], nhdtP2[NG], pdin2[NG], invd2v[NG], aprod2[NG], aprel2[2];
    float alphas[EPL], apH;
    float Alev0, Alev1, Alev2, Alev3, Alev4, Alev5, Aexcl;
    {
        double apd = 1.0, ap4 = 1.0;
        double aprd[EPL];
#pragma unroll
        for (int i = 0; i < EPL; ++i) {
            const int    n = wv * 512 + lane * EPL + i;
            const double p = sqrt(1.0 + 2.0 * (double)n);
            const double d = 1.0 + hdt * (double)(n + 1);
            const double a = 1.0 - hdt * p * p / d;
            upc2[i>>1][i&1]   = (float)(L2E2 * hdt * p);
            nhdtP2[i>>1][i&1] = (float)(-hdt * p);
            pdin2[i>>1][i&1]  = (float)(p / d);
            invd2v[i>>1][i&1] = (float)(2.0 / d);
            alphas[i]         = (float)a;
            aprd[i] = apd;
            aprod2[i>>1][i&1] = (float)apd;
            apd *= a;
            if (i == 4) ap4 = aprd[4];
        }
        apH = (float)(apd / ap4);
#pragma unroll
        for (int i = 4; i < EPL; ++i)
            aprel2[(i-4)>>1][i&1] = (float)(aprd[i] / ap4);
        float A = (float)apd;
        Alev0 = A; A *= dpp_mov<0x111, 0xf>(A, 1.0f);
        Alev1 = A; A *= dpp_mov<0x112, 0xf>(A, 1.0f);
        Alev2 = A; A *= dpp_mov<0x114, 0xf>(A, 1.0f);
        Alev3 = A; A *= dpp_mov<0x118, 0xf>(A, 1.0f);
        Alev4 = A; A *= dpp_mov<0x142, 0xa>(A, 1.0f);
        Alev5 = A; A *= dpp_mov<0x143, 0xc>(A, 1.0f);
        Aexcl = dpp_mov<0x138, 0xf>(A, 1.0f);   // lane0 -> 1 (excl alpha prod)
    }

    const float c2  = (float)L2E2;           //  2*log2e
    const float nc4 = (float)(-2.0 * L2E2);  // -4*log2e  (Hs = nc4*r + c2)
    const float p4  = (float)(2.0 * L2E2);   //  (-Hs = p4*r - c2)
    const v2f  c2v  = (v2f){c2, c2},  nc2v = (v2f){-c2, -c2};
    const v2f  nc4v = (v2f){nc4, nc4}, p4v = (v2f){p4, p4};

    __syncthreads();                         // u_s ready

    // ---- state: r (sigmoid form, h = 1-2r)
    v2f r2[NG];
#pragma unroll
    for (int j = 0; j < NG; ++j) r2[j] = (v2f){0.5f, 0.5f};   // h = 0

#pragma unroll 1
    for (int tick = 0; tick < NCH + NW - 1; ++tick) {
        const int ch = tick - wv;            // this wave's chunk index
        if (0 <= ch && ch < NCH) {
            // ---- bulk register loads: chunk u's and (wave1) wave0 B-totals
            float4 u4[CH/4], Bv4[CH/4];
            {
                const float4* up = (const float4*)&u_s[ch * CH];
#pragma unroll
                for (int q = 0; q < CH/4; ++q) u4[q] = up[q];
            }
            if (wv) {
                const float4* bp = (const float4*)&totB_s[ch * CH];
#pragma unroll
                for (int q = 0; q < CH/4; ++q) Bv4[q] = bp[q];
            }
            float Bacc[CH];

#pragma unroll
            for (int k = 0; k < CH; ++k) {
                const float u  = ((const float*)&u4[k>>2])[k&3];
                const v2f  uu  = (v2f){u, u};

                // ---- head: w = Hs + upc*u (Hs = nc4*r + c2); gamma; -Hs
                v2f w2[NG], gam2[NG], negh[NG];
#pragma unroll
                for (int j = 0; j < NG; ++j) {
                    const v2f au = fma2(upc2[j], uu, c2v);
                    w2[j]   = fma2(nc4v, r2[j], au);
                    gam2[j] = pdin2[j] * w2[j];
                    negh[j] = fma2(p4v, r2[j], nc2v);
                }

                // ---- local affine scan: two 4-deep chains + compose
                v2f Tb2[NG];
                float Tl0 = 0.0f, Tl1 = 0.0f;
#pragma unroll
                for (int i = 0; i < 4; ++i) {
                    Tb2[i>>1][i&1] = Tl0;
                    Tl0 = fmaf(alphas[i], Tl0, gam2[i>>1][i&1]);
                }
#pragma unroll
                for (int i = 4; i < EPL; ++i) {
                    Tb2[i>>1][i&1] = Tl1;
                    Tl1 = fmaf(alphas[i], Tl1, gam2[i>>1][i&1]);
                }
                const v2f T4 = (v2f){Tl0, Tl0};
                Tb2[2] = fma2(aprel2[0], T4, Tb2[2]);      // hi-half fixup
                Tb2[3] = fma2(aprel2[1], T4, Tb2[3]);
                float B = fmaf(apH, Tl0, Tl1);             // lane affine-B

                // ---- cross-lane affine scan (B chain, A's precomputed)
                float Bin;
                Bin = dpp_mov<0x111, 0xf>(B, 0.0f); B = fmaf(Alev0, Bin, B);
                Bin = dpp_mov<0x112, 0xf>(B, 0.0f); B = fmaf(Alev1, Bin, B);
                Bin = dpp_mov<0x114, 0xf>(B, 0.0f); B = fmaf(Alev2, Bin, B);
                Bin = dpp_mov<0x118, 0xf>(B, 0.0f); B = fmaf(Alev3, Bin, B);
                Bin = dpp_mov<0x142, 0xa>(B, 0.0f); B = fmaf(Alev4, Bin, B);
                Bin = dpp_mov<0x143, 0xc>(B, 0.0f); B = fmaf(Alev5, Bin, B);
                Bacc[k] = B;                               // wave0 publishes later

                const float Tst  = dpp_mov<0x138, 0xf>(B, 0.0f); // excl shift
                const float Tin  = wv ? ((const float*)&Bv4[k>>2])[k&3] : 0.0f;
                const float Tent = fmaf(Aexcl, Tin, Tst);
                const v2f  Tev   = (v2f){Tent, Tent};

                // ---- elementwise tail, phase-separated
                v2f Tn[NG], tmp[NG], g2l[NG], e[NG];
#pragma unroll
                for (int j = 0; j < NG; ++j) Tn[j]  = fma2(aprod2[j], Tev, Tb2[j]);
#pragma unroll
                for (int j = 0; j < NG; ++j) tmp[j] = fma2(nhdtP2[j], Tn[j], w2[j]);
#pragma unroll
                for (int j = 0; j < NG; ++j) g2l[j] = fma2(tmp[j], invd2v[j], negh[j]);
#pragma unroll
                for (int j = 0; j < NG; ++j) { e[j].x = EXP2F(g2l[j].x);
                                               e[j].y = EXP2F(g2l[j].y); }
#pragma unroll
                for (int j = 0; j < NG; ++j) e[j] = e[j] + (v2f){1.0f, 1.0f};
#pragma unroll
                for (int j = 0; j < NG; ++j) { r2[j].x = __builtin_amdgcn_rcpf(e[j].x);
                                               r2[j].y = __builtin_amdgcn_rcpf(e[j].y); }
            }

            // wave0: publish the chunk's 16 B-totals (lane 63 holds them)
            if (wv == 0 && lane == 63) {
                float4* tp = (float4*)&totB_s[ch * CH];
#pragma unroll
                for (int q = 0; q < CH/4; ++q)
                    tp[q] = make_float4(Bacc[4*q], Bacc[4*q+1],
                                        Bacc[4*q+2], Bacc[4*q+3]);
            }
        }
        __syncthreads();   // one barrier per CHUNK (16 steps)
    }

    // ---- epilogue: h = 1-2r; tot = dot(h, C) over this wave's 512 elems
    double acc = 0.0;
#pragma unroll
    for (int i = 0; i < EPL; ++i) {
        const float hi = fmaf(-2.0f, r2[i>>1][i&1], 1.0f);
        acc = fma((double)C[wv * 512 + lane * EPL + i], (double)hi, acc);
    }
#pragma unroll
    for (int off = 32; off > 0; off >>= 1)
        acc += __shfl_down(acc, off, 64);
    if (lane == 0) part_s[wv] = acc;
    __syncthreads();
    if (tid < OUT_DIM) {
        const double tot = part_s[0] + part_s[1];
        out[b * OUT_DIM + tid] =
            (float)fma(tot, (double)W[tid], (double)bvec[tid]);
    }
}

extern "C" void kernel_launch(void* const* d_in, const int* in_sizes, int n_in,
                              void* d_out, int out_size, void* d_ws, size_t ws_size,
                              hipStream_t stream) {
    const float* x  = (const float*)d_in[0];   // (512, 784, 1)
    const float* C  = (const float*)d_in[1];   // (1, 1024)
    const float* W  = (const float*)d_in[2];   // (1, 10)
    const float* bv = (const float*)d_in[3];   // (10,)
    float* out      = (float*)d_out;           // (512, 10)
    hipLaunchKernelGGL(ssm_hippo_scan, dim3(512), dim3(128), 0, stream,
                       x, C, W, bv, out);
}

// Round 10
// 267.646 us; speedup vs baseline: 1.4490x; 1.3143x over previous
//
#include <hip/hip_runtime.h>
#include <math.h>

// SSM_18597208391915: HiPPO-LegT recurrence, O(N) semiseparable solve.
// Ad = (I-cA)^{-1}(I+cA) = 2M - I  =>  h' = tanh(2*M(h + c*u*P) - h).
// R10: NW=4 chunked skewed wave pipeline at 2 WAVES/SIMD.
// R9 post-mortem: per-wave issue 405 cyc/step (measured busy) but 536 cyc
// exposed stall at 1 wave/SIMD - scan/DPP/trans latencies naked. Fix needs
// CO-RESIDENT INDEPENDENT waves: NW=4 hidden split (EPL=4, 256-thr blocks)
// -> 2048 waves = 2/SIMD, and each SIMD's 2 waves are from DIFFERENT blocks
// (2 blocks/CU) = different batch elements = fully independent stall hiding.
// Mechanics from R9 (proven): 16-step all-register inner loop, one barrier
// per chunk, bulk float4 LDS comms at chunk edges, inter-wave composition
// via precomputed fp64 Phi products -> Tin[16] registers before the loop.

#define SEQ     784
#define OUT_DIM 10
#define NW      4
#define CH      16            // steps per chunk
#define NCH     (SEQ/CH)      // 49
#define EPL     4             // elems/lane: NW*64*EPL = 1024 = HIDDEN
#define NG      (EPL/2)

typedef float v2f __attribute__((ext_vector_type(2)));

#if __has_builtin(__builtin_elementwise_fma)
__device__ __forceinline__ v2f fma2(v2f a, v2f b, v2f c) {
    return __builtin_elementwise_fma(a, b, c);
}
#else
__device__ __forceinline__ v2f fma2(v2f a, v2f b, v2f c) {
    v2f r; r.x = fmaf(a.x, b.x, c.x); r.y = fmaf(a.y, b.y, c.y); return r;
}
#endif

#if __has_builtin(__builtin_amdgcn_exp2f)
#define EXP2F(x) __builtin_amdgcn_exp2f(x)
#else
#define EXP2F(x) __expf(0.69314718055994531f * (x))
#endif

// DPP move: result = src shuffled per CTRL; invalid/masked lanes get `old`.
template<int CTRL, int ROW_MASK>
__device__ __forceinline__ float dpp_mov(float src, float old) {
    return __int_as_float(__builtin_amdgcn_update_dpp(
        __float_as_int(old), __float_as_int(src), CTRL, ROW_MASK, 0xf, false));
}
// DPP ctrls: row_shr:N = 0x110|N, row_bcast15 = 0x142, row_bcast31 = 0x143,
//            wave_shr:1 = 0x138 (whole-wave shift down one lane)

__global__ __launch_bounds__(256, 2)
void ssm_hippo_scan(const float* __restrict__ x,     // (512, 784)
                    const float* __restrict__ C,     // (1024)
                    const float* __restrict__ W,     // (10)
                    const float* __restrict__ bvec,  // (10)
                    float* __restrict__ out)         // (512, 10)
{
    const int b    = blockIdx.x;
    const int tid  = threadIdx.x;
    const int wv   = tid >> 6;       // wave w owns elems [w*256, w*256+256)
    const int lane = tid & 63;

    __shared__ __align__(16) float u_s[SEQ];
    __shared__ __align__(16) float totB_s[NW-1][SEQ]; // inclusive-B streams
    __shared__ double part_s[NW];

    for (int t = tid; t < SEQ; t += 256) u_s[t] = x[b * SEQ + t];

    const double hdt  = 0.5 / (double)SEQ;            // c = dt/2
    const double L2E2 = 2.0 * 1.4426950408889634;     // 2*log2(e)

    // ---- per-element constants (n = wv*256 + lane*EPL + i), fp64-derived
    v2f upc2[NG], nhdtP2[NG], pdin2[NG], invd2v[NG], aprod2[NG];
    v2f aprel2;                 // {1, alphas[2]}: hi-chain fixup
    float alphas[EPL], apH;
    float Alev0, Alev1, Alev2, Alev3, Alev4, Alev5, Aexcl;
    {
        double apd = 1.0;
#pragma unroll
        for (int i = 0; i < EPL; ++i) {
            const int    n = wv * 256 + lane * EPL + i;
            const double p = sqrt(1.0 + 2.0 * (double)n);
            const double d = 1.0 + hdt * (double)(n + 1);
            const double a = 1.0 - hdt * p * p / d;
            upc2[i>>1][i&1]   = (float)(L2E2 * hdt * p);
            nhdtP2[i>>1][i&1] = (float)(-hdt * p);
            pdin2[i>>1][i&1]  = (float)(p / d);
            invd2v[i>>1][i&1] = (float)(2.0 / d);
            alphas[i]         = (float)a;
            aprod2[i>>1][i&1] = (float)apd;
            apd *= a;
        }
        aprel2 = (v2f){1.0f, alphas[2]};
        apH    = alphas[2] * alphas[3];
        float A = (float)apd;
        Alev0 = A; A *= dpp_mov<0x111, 0xf>(A, 1.0f);
        Alev1 = A; A *= dpp_mov<0x112, 0xf>(A, 1.0f);
        Alev2 = A; A *= dpp_mov<0x114, 0xf>(A, 1.0f);
        Alev3 = A; A *= dpp_mov<0x118, 0xf>(A, 1.0f);
        Alev4 = A; A *= dpp_mov<0x142, 0xa>(A, 1.0f);
        Alev5 = A; A *= dpp_mov<0x143, 0xc>(A, 1.0f);
        Aexcl = dpp_mov<0x138, 0xf>(A, 1.0f);   // lane0 -> 1 (excl alpha prod)
    }

    // inter-wave composition: Tin(w)[s] = sum_{v<w} cin_v * B_v[s],
    // cin_v = prod_{v<z<w} Phi_z; Phi_z = prod alpha_n over wave z
    //       = prod (1 - c n)/(1 + c(n+1))  (closed form)
    float cF1 = 0.0f, cF2 = 0.0f, cF12 = 0.0f;
    {
        double n1 = 1.0, d1 = 1.0, n2 = 1.0, d2 = 1.0;
        for (int n = 256; n < 512; ++n) {
            n1 *= 1.0 - hdt * (double)n; d1 *= 1.0 + hdt * (double)(n + 1);
        }
        for (int n = 512; n < 768; ++n) {
            n2 *= 1.0 - hdt * (double)n; d2 *= 1.0 + hdt * (double)(n + 1);
        }
        const double Phi1 = n1 / d1, Phi2 = n2 / d2;
        cF1 = (float)Phi1; cF2 = (float)Phi2; cF12 = (float)(Phi1 * Phi2);
    }

    const float c2  = (float)L2E2;           //  2*log2e
    const float nc4 = (float)(-2.0 * L2E2);  // -4*log2e  (Hs = nc4*r + c2)
    const float p4  = (float)(2.0 * L2E2);   //  (-Hs = p4*r - c2)
    const v2f  c2v  = (v2f){c2, c2},  nc2v = (v2f){-c2, -c2};
    const v2f  nc4v = (v2f){nc4, nc4}, p4v = (v2f){p4, p4};

    __syncthreads();                         // u_s ready

    // ---- state: r (sigmoid form, h = 1-2r)
    v2f r2[NG];
#pragma unroll
    for (int j = 0; j < NG; ++j) r2[j] = (v2f){0.5f, 0.5f};   // h = 0

#pragma unroll 1
    for (int tick = 0; tick < NCH + NW - 1; ++tick) {
        const int ch = tick - wv;            // this wave's chunk index
        if (0 <= ch && ch < NCH) {
            // ---- bulk register loads: u's and incoming-B composition
            float4 u4[CH/4];
            float  Tin[CH];
            {
                const float4* up = (const float4*)&u_s[ch * CH];
#pragma unroll
                for (int q = 0; q < CH/4; ++q) u4[q] = up[q];
            }
            if (wv == 0) {
#pragma unroll
                for (int k = 0; k < CH; ++k) Tin[k] = 0.0f;
            } else if (wv == 1) {
                const float4* b0 = (const float4*)&totB_s[0][ch * CH];
#pragma unroll
                for (int q = 0; q < CH/4; ++q) {
                    const float4 v0 = b0[q];
                    Tin[4*q+0] = v0.x; Tin[4*q+1] = v0.y;
                    Tin[4*q+2] = v0.z; Tin[4*q+3] = v0.w;
                }
            } else if (wv == 2) {
                const float4* b0 = (const float4*)&totB_s[0][ch * CH];
                const float4* b1 = (const float4*)&totB_s[1][ch * CH];
#pragma unroll
                for (int q = 0; q < CH/4; ++q) {
                    const float4 v0 = b0[q], v1 = b1[q];
                    Tin[4*q+0] = fmaf(cF1, v0.x, v1.x);
                    Tin[4*q+1] = fmaf(cF1, v0.y, v1.y);
                    Tin[4*q+2] = fmaf(cF1, v0.z, v1.z);
                    Tin[4*q+3] = fmaf(cF1, v0.w, v1.w);
                }
            } else {
                const float4* b0 = (const float4*)&totB_s[0][ch * CH];
                const float4* b1 = (const float4*)&totB_s[1][ch * CH];
                const float4* b2 = (const float4*)&totB_s[2][ch * CH];
#pragma unroll
                for (int q = 0; q < CH/4; ++q) {
                    const float4 v0 = b0[q], v1 = b1[q], v2 = b2[q];
                    Tin[4*q+0] = fmaf(cF12, v0.x, fmaf(cF2, v1.x, v2.x));
                    Tin[4*q+1] = fmaf(cF12, v0.y, fmaf(cF2, v1.y, v2.y));
                    Tin[4*q+2] = fmaf(cF12, v0.z, fmaf(cF2, v1.z, v2.z));
                    Tin[4*q+3] = fmaf(cF12, v0.w, fmaf(cF2, v1.w, v2.w));
                }
            }
            float Bacc[CH];

#pragma unroll
            for (int k = 0; k < CH; ++k) {
                const float u  = ((const float*)&u4[k>>2])[k&3];
                const v2f  uu  = (v2f){u, u};

                // ---- head: w = Hs + upc*u (Hs = nc4*r + c2); gamma; -Hs
                v2f w2[NG], gam2[NG], negh[NG];
#pragma unroll
                for (int j = 0; j < NG; ++j) {
                    const v2f au = fma2(upc2[j], uu, c2v);
                    w2[j]   = fma2(nc4v, r2[j], au);
                    gam2[j] = pdin2[j] * w2[j];
                    negh[j] = fma2(p4v, r2[j], nc2v);
                }

                // ---- local affine scan: two 2-deep chains + compose
                v2f Tb2[NG];
                Tb2[0] = (v2f){0.0f, gam2[0].x};
                const float Tl0 = fmaf(alphas[1], gam2[0].x, gam2[0].y);
                Tb2[1] = (v2f){0.0f, gam2[1].x};
                const float Tl1 = fmaf(alphas[3], gam2[1].x, gam2[1].y);
                Tb2[1] = fma2(aprel2, (v2f){Tl0, Tl0}, Tb2[1]); // hi fixup
                float B = fmaf(apH, Tl0, Tl1);             // lane affine-B

                // ---- cross-lane affine scan (B chain, A's precomputed)
                float Bin;
                Bin = dpp_mov<0x111, 0xf>(B, 0.0f); B = fmaf(Alev0, Bin, B);
                Bin = dpp_mov<0x112, 0xf>(B, 0.0f); B = fmaf(Alev1, Bin, B);
                Bin = dpp_mov<0x114, 0xf>(B, 0.0f); B = fmaf(Alev2, Bin, B);
                Bin = dpp_mov<0x118, 0xf>(B, 0.0f); B = fmaf(Alev3, Bin, B);
                Bin = dpp_mov<0x142, 0xa>(B, 0.0f); B = fmaf(Alev4, Bin, B);
                Bin = dpp_mov<0x143, 0xc>(B, 0.0f); B = fmaf(Alev5, Bin, B);
                Bacc[k] = B;                               // publish later

                const float Tst  = dpp_mov<0x138, 0xf>(B, 0.0f); // excl shift
                const float Tent = fmaf(Aexcl, Tin[k], Tst);
                const v2f  Tev   = (v2f){Tent, Tent};

                // ---- elementwise tail, phase-separated
                v2f Tn[NG], tmp[NG], g2l[NG], e[NG];
#pragma unroll
                for (int j = 0; j < NG; ++j) Tn[j]  = fma2(aprod2[j], Tev, Tb2[j]);
#pragma unroll
                for (int j = 0; j < NG; ++j) tmp[j] = fma2(nhdtP2[j], Tn[j], w2[j]);
#pragma unroll
                for (int j = 0; j < NG; ++j) g2l[j] = fma2(tmp[j], invd2v[j], negh[j]);
#pragma unroll
                for (int j = 0; j < NG; ++j) { e[j].x = EXP2F(g2l[j].x);
                                               e[j].y = EXP2F(g2l[j].y); }
#pragma unroll
                for (int j = 0; j < NG; ++j) e[j] = e[j] + (v2f){1.0f, 1.0f};
#pragma unroll
                for (int j = 0; j < NG; ++j) { r2[j].x = __builtin_amdgcn_rcpf(e[j].x);
                                               r2[j].y = __builtin_amdgcn_rcpf(e[j].y); }
            }

            // publish this wave's chunk B-totals (lane 63 holds them)
            if (wv < NW - 1 && lane == 63) {
                float4* tp = (float4*)&totB_s[wv][ch * CH];
#pragma unroll
                for (int q = 0; q < CH/4; ++q)
                    tp[q] = make_float4(Bacc[4*q], Bacc[4*q+1],
                                        Bacc[4*q+2], Bacc[4*q+3]);
            }
        }
        __syncthreads();   // one barrier per CHUNK (16 steps)
    }

    // ---- epilogue: h = 1-2r; tot = dot(h, C) over this wave's 256 elems
    double acc = 0.0;
#pragma unroll
    for (int i = 0; i < EPL; ++i) {
        const float hi = fmaf(-2.0f, r2[i>>1][i&1], 1.0f);
        acc = fma((double)C[wv * 256 + lane * EPL + i], (double)hi, acc);
    }
#pragma unroll
    for (int off = 32; off > 0; off >>= 1)
        acc += __shfl_down(acc, off, 64);
    if (lane == 0) part_s[wv] = acc;
    __syncthreads();
    if (tid < OUT_DIM) {
        const double tot = part_s[0] + part_s[1] + part_s[2] + part_s[3];
        out[b * OUT_DIM + tid] =
            (float)fma(tot, (double)W[tid], (double)bvec[tid]);
    }
}

extern "C" void kernel_launch(void* const* d_in, const int* in_sizes, int n_in,
                              void* d_out, int out_size, void* d_ws, size_t ws_size,
                              hipStream_t stream) {
    const float* x  = (const float*)d_in[0];   // (512, 784, 1)
    const float* C  = (const float*)d_in[1];   // (1, 1024)
    const float* W  = (const float*)d_in[2];   // (1, 10)
    const float* bv = (const float*)d_in[3];   // (10,)
    float* out      = (float*)d_out;           // (512, 10)
    hipLaunchKernelGGL(ssm_hippo_scan, dim3(512), dim3(256), 0, stream,
                       x, C, W, bv, out);
}